// Round 4
// baseline (3273.043 us; speedup 1.0000x reference)
//
#include <hip/hip_runtime.h>
#include <hip/hip_bf16.h>
#include <math.h>

#define B_   128
#define T_   2048
#define DIN  64
#define H_   128
#define WH_  256
#define WY_  256
#define DOUT 64

typedef __attribute__((ext_vector_type(8))) short short8;
typedef __attribute__((ext_vector_type(4))) float floatx4;

// Raw barrier: wait LDS ops only (global stores stay in flight).
__device__ __forceinline__ void bar_lds() {
    asm volatile("s_waitcnt lgkmcnt(0)\n\ts_barrier" ::: "memory");
}

__device__ __forceinline__ short bf16_hi(float f) {
    __hip_bfloat16 h = __float2bfloat16(f);
    return *reinterpret_cast<short*>(&h);
}
__device__ __forceinline__ float bf16_val(short s) {
    __hip_bfloat16 h = *reinterpret_cast<__hip_bfloat16*>(&s);
    return __bfloat162float(h);
}

// ---------------- Phase 1: sequential recurrence, fp32 VALU ----------------
// 128 WGs (1 batch row) x 512 threads. 2 barriers/step; shfl-based reduces.
// GEMV1: f1 = wave*32+(lane&31), K-half kh=lane>>5 (96 each) -> shfl_xor(32)
// GEMV2: f2 = wave*16+(lane&15), K-quarter kq=lane>>4 (64 each) -> 2 shfls
__global__ __launch_bounds__(512, 2) void rnn_phase1(
    const float* __restrict__ x,
    const float* __restrict__ hW1, const float* __restrict__ hb1,
    const float* __restrict__ hW2, const float* __restrict__ hb2,
    __hip_bfloat16* __restrict__ HallB,  // [T_*B_, H_] bf16
    float* __restrict__ outF)            // d_out; hfinal at tail (fp32)
{
    const int b    = blockIdx.x;
    const int tid  = threadIdx.x;
    const int wave = tid >> 6, lane = tid & 63;

    __shared__ float hx[192];        // [0..127]=h fp32, [128..191]=x_t
    __shared__ float sl[256];

    const int f1 = wave * 32 + (lane & 31), kh = lane >> 5;
    const int f2 = wave * 16 + (lane & 15), kq = lane >> 4;

    float W1r[96];
#pragma unroll
    for (int j = 0; j < 96; j += 4)
        *(float4*)&W1r[j] = *(const float4*)&hW1[f1 * 192 + kh * 96 + j];
    float W2r[64];
#pragma unroll
    for (int j = 0; j < 64; j += 4)
        *(float4*)&W2r[j] = *(const float4*)&hW2[f2 * 256 + kq * 64 + j];

    const float b1 = hb1[f1];
    const float b2 = hb2[f2];

    if (tid < 128) hx[tid] = 0.f;
    float xreg = 0.f;
    if (tid >= 448) {
        const int l = tid - 448;
        const long xb = (long)b * (T_ * DIN);
        hx[128 + l] = x[xb + l];        // x_0
        xreg        = x[xb + DIN + l];  // x_1
    }
    __syncthreads();

    for (int t = 0; t < T_; ++t) {
        // ---- A: GEMV1 (K-half) + shfl reduce + silu -> sl
        {
            float a0 = 0.f, a1 = 0.f, a2 = 0.f, a3 = 0.f;
            const float* hp = &hx[kh * 96];   // broadcast reads (2 addrs/wave)
#pragma unroll
            for (int j = 0; j < 96; j += 8) {
                const float4 u4 = *(const float4*)&hp[j];
                const float4 v4 = *(const float4*)&hp[j + 4];
                a0 += u4.x * W1r[j + 0] + u4.y * W1r[j + 1];
                a1 += u4.z * W1r[j + 2] + u4.w * W1r[j + 3];
                a2 += v4.x * W1r[j + 4] + v4.y * W1r[j + 5];
                a3 += v4.z * W1r[j + 6] + v4.w * W1r[j + 7];
            }
            float v = (a0 + a1) + (a2 + a3);
            v += __shfl_xor(v, 32, 64);       // combine K-halves
            v += b1;
            const float s = v / (1.f + expf(-v));
            if (lane < 32) sl[f1] = s;
        }
        bar_lds();

        // ---- B: x_{t+1} install + prefetch; GEMV2 + 2 shfls -> h_new
        if (tid >= 448) {
            const int l = tid - 448;
            if (t + 1 < T_) hx[128 + l] = xreg;
            const int tn = (t + 2 < T_) ? (t + 2) : (T_ - 1);
            xreg = x[(long)b * (T_ * DIN) + (long)tn * DIN + l];
        }
        {
            float c0 = 0.f, c1 = 0.f, c2 = 0.f, c3 = 0.f;
            const float* sp = &sl[kq * 64];   // broadcast reads (4 addrs/wave)
#pragma unroll
            for (int j = 0; j < 64; j += 8) {
                const float4 u4 = *(const float4*)&sp[j];
                const float4 v4 = *(const float4*)&sp[j + 4];
                c0 += u4.x * W2r[j + 0] + u4.y * W2r[j + 1];
                c1 += u4.z * W2r[j + 2] + u4.w * W2r[j + 3];
                c2 += v4.x * W2r[j + 4] + v4.y * W2r[j + 5];
                c3 += v4.z * W2r[j + 6] + v4.w * W2r[j + 7];
            }
            float hv = (c0 + c1) + (c2 + c3);
            hv += __shfl_xor(hv, 16, 64);     // combine K-quarters
            hv += __shfl_xor(hv, 32, 64);
            hv += b2;
            if (lane < 16) {
                hx[f2] = hv;                  // fp32 recurrent state
                HallB[((long)t * B_ + b) * H_ + f2] = __float2bfloat16(hv);
            }
        }
        bar_lds();
    }

    if (tid < 128)
        outF[(long)B_ * T_ * DOUT + (long)b * H_ + tid] = hx[tid];
}

// -------- pre-split y-weights into MFMA-frag-linear bf16 hi/lo -------------
// Y1f: [nt(16)][ks(4)][lane(64)][j(8)] hi, +32768 lo   (shorts)
// Y2f: [nt2(4)][ks(8)][lane(64)][j(8)] hi, +16384 lo
__global__ __launch_bounds__(256) void presplit(
    const float* __restrict__ yW1, const float* __restrict__ yW2,
    short* __restrict__ Y1f, short* __restrict__ Y2f)
{
    const int i = blockIdx.x * 256 + threadIdx.x;
    if (i < 32768) {
        const int j = i & 7, lane = (i >> 3) & 63, ks = (i >> 9) & 3, nt = i >> 11;
        const float v = yW1[(nt * 16 + (lane & 15)) * 128 + (lane >> 4) * 8 + ks * 32 + j];
        const short h = bf16_hi(v);
        Y1f[i]         = h;
        Y1f[32768 + i] = bf16_hi(v - bf16_val(h));
    }
    if (i < 16384) {
        const int j = i & 7, lane = (i >> 3) & 63, ks = (i >> 9) & 7, nt2 = i >> 12;
        const float v = yW2[(nt2 * 16 + (lane & 15)) * 256 + (lane >> 4) * 8 + ks * 32 + j];
        const short h = bf16_hi(v);
        Y2f[i]         = h;
        Y2f[16384 + i] = bf16_hi(v - bf16_val(h));
    }
}

// ---------------- Phase 2: y-MLP via MFMA -----------------
// 1024 WGs x 4 waves; each wave does 2 pairs of 16-row tiles (32 rows/pair).
// A = bf16 Hall rows (direct frag load); B = presplit hi/lo weight frags.
__global__ __launch_bounds__(256, 2) void rnn_phase2(
    const __hip_bfloat16* __restrict__ HallB,
    const float* __restrict__ yb1, const float* __restrict__ yb2,
    const short* __restrict__ Y1f, const short* __restrict__ Y2f,
    float* __restrict__ out)
{
    __shared__ short u_lds[4][2][16 * 256];   // per-wave 2 tiles x 8KB

    const int tid  = threadIdx.x;
    const int wave = tid >> 6, lane = tid & 63;
    const int l15  = lane & 15, lg = lane >> 4;
    const int wglobal = blockIdx.x * 4 + wave;     // 0..4095
    const floatx4 zero4 = {0.f, 0.f, 0.f, 0.f};
    const short* Hs = (const short*)HallB;

    for (int it = 0; it < 2; ++it) {
        const long pair = (long)wglobal + 4096L * it;   // 0..8191
        const long r0   = pair * 32;

        short8 aH[2][4];
#pragma unroll
        for (int p = 0; p < 2; ++p)
#pragma unroll
            for (int ks = 0; ks < 4; ++ks)
                aH[p][ks] = *(const short8*)(Hs + (r0 + p * 16 + l15) * 128 + lg * 8 + ks * 32);

        // ---- GEMM1 + silu -> u (bf16) in LDS, XOR-swizzled
#pragma unroll
        for (int nt = 0; nt < 16; ++nt) {
            floatx4 accA = zero4, accB = zero4;
#pragma unroll
            for (int ks = 0; ks < 4; ++ks) {
                const short8 bhi = *(const short8*)(Y1f + ((nt * 4 + ks) * 512 + lane * 8));
                const short8 blo = *(const short8*)(Y1f + 32768 + ((nt * 4 + ks) * 512 + lane * 8));
                accA = __builtin_amdgcn_mfma_f32_16x16x32_bf16(aH[0][ks], bhi, accA, 0, 0, 0);
                accA = __builtin_amdgcn_mfma_f32_16x16x32_bf16(aH[0][ks], blo, accA, 0, 0, 0);
                accB = __builtin_amdgcn_mfma_f32_16x16x32_bf16(aH[1][ks], bhi, accB, 0, 0, 0);
                accB = __builtin_amdgcn_mfma_f32_16x16x32_bf16(aH[1][ks], blo, accB, 0, 0, 0);
            }
            const int col  = nt * 16 + l15;
            const float bias = yb1[col];
#pragma unroll
            for (int r = 0; r < 4; ++r) {
                const int row = lg * 4 + r;
                int byte = row * 512 + col * 2;
                byte ^= ((row & 7) << 4);
                float v = accA[r] + bias;
                *(short*)((char*)u_lds[wave][0] + byte) = bf16_hi(v / (1.f + __expf(-v)));
                v = accB[r] + bias;
                *(short*)((char*)u_lds[wave][1] + byte) = bf16_hi(v / (1.f + __expf(-v)));
            }
        }
        asm volatile("s_waitcnt lgkmcnt(0)" ::: "memory");

        // ---- GEMM2
        floatx4 acc2A[4] = {zero4, zero4, zero4, zero4};
        floatx4 acc2B[4] = {zero4, zero4, zero4, zero4};
#pragma unroll
        for (int ks = 0; ks < 8; ++ks) {
            int byte = l15 * 512 + (lg * 8 + ks * 32) * 2;
            byte ^= ((l15 & 7) << 4);
            const short8 aUa = *(const short8*)((char*)u_lds[wave][0] + byte);
            const short8 aUb = *(const short8*)((char*)u_lds[wave][1] + byte);
#pragma unroll
            for (int nt = 0; nt < 4; ++nt) {
                const short8 bhi = *(const short8*)(Y2f + ((nt * 8 + ks) * 512 + lane * 8));
                const short8 blo = *(const short8*)(Y2f + 16384 + ((nt * 8 + ks) * 512 + lane * 8));
                acc2A[nt] = __builtin_amdgcn_mfma_f32_16x16x32_bf16(aUa, bhi, acc2A[nt], 0, 0, 0);
                acc2A[nt] = __builtin_amdgcn_mfma_f32_16x16x32_bf16(aUa, blo, acc2A[nt], 0, 0, 0);
                acc2B[nt] = __builtin_amdgcn_mfma_f32_16x16x32_bf16(aUb, bhi, acc2B[nt], 0, 0, 0);
                acc2B[nt] = __builtin_amdgcn_mfma_f32_16x16x32_bf16(aUb, blo, acc2B[nt], 0, 0, 0);
            }
        }

        // ---- epilogue: bias + fp32 store (D: col=l15+16nt, row=lg*4+r)
#pragma unroll
        for (int nt = 0; nt < 4; ++nt) {
            const int col  = nt * 16 + l15;
            const float bias = yb2[col];
#pragma unroll
            for (int r = 0; r < 4; ++r) {
                {
                    const long R  = r0 + lg * 4 + r;         // tile A
                    const long bb = R & (B_ - 1);
                    const long tt = R >> 7;
                    out[bb * (T_ * DOUT) + tt * DOUT + col] = acc2A[nt][r] + bias;
                }
                {
                    const long R  = r0 + 16 + lg * 4 + r;    // tile B
                    const long bb = R & (B_ - 1);
                    const long tt = R >> 7;
                    out[bb * (T_ * DOUT) + tt * DOUT + col] = acc2B[nt][r] + bias;
                }
            }
        }
        // same-wave DS ordering makes next-iteration u writes safe (in-order pipe)
    }
}

extern "C" void kernel_launch(void* const* d_in, const int* in_sizes, int n_in,
                              void* d_out, int out_size, void* d_ws, size_t ws_size,
                              hipStream_t stream) {
    const float* x   = (const float*)d_in[0];
    const float* hW1 = (const float*)d_in[1];
    const float* hb1 = (const float*)d_in[2];
    const float* hW2 = (const float*)d_in[3];
    const float* hb2 = (const float*)d_in[4];
    const float* yW1 = (const float*)d_in[5];
    const float* yb1 = (const float*)d_in[6];
    const float* yW2 = (const float*)d_in[7];
    const float* yb2 = (const float*)d_in[8];

    float* out = (float*)d_out;
    __hip_bfloat16* HallB = (__hip_bfloat16*)d_ws;               // 64 MiB
    const size_t hallBytes = (size_t)T_ * B_ * H_ * sizeof(__hip_bfloat16);
    short* Y1f = (short*)((char*)d_ws + hallBytes);              // 128 KB (hi+lo)
    short* Y2f = Y1f + 65536;                                    // 64 KB

    rnn_phase1<<<128, 512, 0, stream>>>(x, hW1, hb1, hW2, hb2, HallB, out);
    presplit<<<128, 256, 0, stream>>>(yW1, yW2, Y1f, Y2f);
    rnn_phase2<<<1024, 256, 0, stream>>>(HallB, yb1, yb2, Y1f, Y2f, out);
}